// Round 4
// baseline (55.367 us; speedup 1.0000x reference)
//
#include <hip/hip_runtime.h>

#define BATCH 8
#define SEQ 8192
#define DIM 1024
#define ROWS_PER_BLOCK 4

typedef float f32x4 __attribute__((ext_vector_type(4)));

// One 1024-thread block per batch. Each thread handles 8 consecutive
// positions. Single pass:
//   1. per-block detection of u8-vs-int32 boundary storage (bytes at
//      offset%4!=0 are all zero iff int32 0/1 little-endian),
//   2. wave-level shfl_up inclusive scan of per-thread boundary counts,
//   3. cross-wave exclusive scan via LDS,
//   4. stable-partition dest for each position; record source row while
//      dest < MC; write num_tokens (fp32) for output 1.
__global__ __launch_bounds__(1024) void scan_kernel(
    const void* __restrict__ bnd, int* __restrict__ srcmap,
    float* __restrict__ ntok_out, int MC) {
    const int b = blockIdx.x;
    const int t = threadIdx.x;          // 0..1023
    const int lane = t & 63;
    const int wid = t >> 6;             // 0..15

    __shared__ int sh_u8;
    __shared__ int wave_tot[16];
    __shared__ int wave_pref[17];

    if (t == 0) sh_u8 = 0;
    __syncthreads();

    const unsigned char* p8 = (const unsigned char*)bnd + (size_t)b * SEQ;
    const unsigned long long raw = ((const unsigned long long*)p8)[t];
    // bytes at local j=1,2,3,5,6,7 have global offset %4 != 0
    if (raw & 0xFFFFFF00FFFFFF00ull) sh_u8 = 1;  // benign same-value race
    __syncthreads();
    const bool u8 = (sh_u8 != 0);

    // bits[j] = boundary at position t*8+j
    unsigned int bits = 0;
    if (u8) {
#pragma unroll
        for (int j = 0; j < 8; ++j)
            if ((raw >> (8 * j)) & 0xFFull) bits |= 1u << j;
    } else {
        const int4* p32 = (const int4*)((const int*)bnd + (size_t)b * SEQ);
        const int4 q0 = p32[t * 2];
        const int4 q1 = p32[t * 2 + 1];
        bits = (q0.x != 0) | ((q0.y != 0) << 1) | ((q0.z != 0) << 2) |
               ((q0.w != 0) << 3) | ((q1.x != 0) << 4) | ((q1.y != 0) << 5) |
               ((q1.z != 0) << 6) | ((q1.w != 0) << 7);
    }
    const int c = __popc(bits);

    // wave-level inclusive scan of c
    int scan = c;
#pragma unroll
    for (int off = 1; off < 64; off <<= 1) {
        const int n = __shfl_up(scan, off);
        if (lane >= off) scan += n;
    }
    const int excl = scan - c;
    if (lane == 63) wave_tot[wid] = scan;
    __syncthreads();
    if (t == 0) {
        int acc = 0;
#pragma unroll
        for (int i = 0; i < 16; ++i) { wave_pref[i] = acc; acc += wave_tot[i]; }
        wave_pref[16] = acc;
    }
    __syncthreads();

    const int total = wave_pref[16];
    int P = wave_pref[wid] + excl;      // boundaries strictly before t*8
    const int s0 = t * 8;
    int* __restrict__ sm = srcmap + (size_t)b * MC;
#pragma unroll
    for (int j = 0; j < 8; ++j) {
        const int s = s0 + j;
        const int v = (bits >> j) & 1;
        const int dest = v ? P : (total + s - P);
        if (dest < MC) sm[dest] = s;
        P += v;
    }
    if (t == 0) ntok_out[b] = (float)total;  // exact in fp32 (<= 8192)
}

// ROWS_PER_BLOCK output rows per 256-thread block. Each thread moves one
// f32x4 per row. All loads issued before stores -> 4x MLP per wave.
// Non-temporal: streaming data, never re-read, keep it out of L2.
__global__ __launch_bounds__(256) void gather_kernel(
    const float* __restrict__ x, const int* __restrict__ srcmap,
    float* __restrict__ out, int MC) {
    const int b = blockIdx.y;
    const int c0 = blockIdx.x * ROWS_PER_BLOCK;
    const int cnt = min(ROWS_PER_BLOCK, MC - c0);
    const int* __restrict__ sm = srcmap + (size_t)b * MC;
    const f32x4* __restrict__ xb = (const f32x4*)(x + (size_t)b * SEQ * DIM);
    f32x4* __restrict__ ob = (f32x4*)(out + (size_t)b * MC * DIM);
    const int t = threadIdx.x;  // 0..255, DIM/4 = 256 f32x4 per row

    f32x4 v[ROWS_PER_BLOCK];
#pragma unroll
    for (int j = 0; j < ROWS_PER_BLOCK; ++j) {
        if (j < cnt) {
            const int s = sm[c0 + j];
            v[j] = __builtin_nontemporal_load(&xb[(size_t)s * (DIM / 4) + t]);
        }
    }
#pragma unroll
    for (int j = 0; j < ROWS_PER_BLOCK; ++j) {
        if (j < cnt) {
            __builtin_nontemporal_store(v[j], &ob[(size_t)(c0 + j) * (DIM / 4) + t]);
        }
    }
}

extern "C" void kernel_launch(void* const* d_in, const int* in_sizes, int n_in,
                              void* d_out, int out_size, void* d_ws, size_t ws_size,
                              hipStream_t stream) {
    const float* x = (const float*)d_in[0];
    const void* bnd = d_in[1];
    float* out = (float*)d_out;

    // out layout: [B, MC, D] hidden states, then [B] num_tokens (as float32)
    const int MC = (out_size - BATCH) / (BATCH * DIM);

    int* srcmap = (int*)d_ws;

    scan_kernel<<<BATCH, 1024, 0, stream>>>(bnd, srcmap,
                                            out + (size_t)BATCH * MC * DIM, MC);
    gather_kernel<<<dim3((MC + ROWS_PER_BLOCK - 1) / ROWS_PER_BLOCK, BATCH),
                    256, 0, stream>>>(x, srcmap, out, MC);
}

// Round 5
// 49.528 us; speedup vs baseline: 1.1179x; 1.1179x over previous
//
#include <hip/hip_runtime.h>

#define BATCH 8
#define SEQ 8192
#define DIM 1024

// One 1024-thread block per batch. Each thread handles 8 consecutive
// positions. Single pass:
//   1. per-block detection of u8-vs-int32 boundary storage (bytes at
//      offset%4!=0 are all zero iff int32 0/1 little-endian),
//   2. wave-level shfl_up inclusive scan of per-thread boundary counts,
//   3. cross-wave exclusive scan via LDS,
//   4. stable-partition dest for each position; record source row while
//      dest < MC; write num_tokens (fp32) for output 1.
__global__ __launch_bounds__(1024) void scan_kernel(
    const void* __restrict__ bnd, int* __restrict__ srcmap,
    float* __restrict__ ntok_out, int MC) {
    const int b = blockIdx.x;
    const int t = threadIdx.x;          // 0..1023
    const int lane = t & 63;
    const int wid = t >> 6;             // 0..15

    __shared__ int sh_u8;
    __shared__ int wave_tot[16];
    __shared__ int wave_pref[17];

    if (t == 0) sh_u8 = 0;
    __syncthreads();

    const unsigned char* p8 = (const unsigned char*)bnd + (size_t)b * SEQ;
    const unsigned long long raw = ((const unsigned long long*)p8)[t];
    // bytes at local j=1,2,3,5,6,7 have global offset %4 != 0
    if (raw & 0xFFFFFF00FFFFFF00ull) sh_u8 = 1;  // benign same-value race
    __syncthreads();
    const bool u8 = (sh_u8 != 0);

    // bits[j] = boundary at position t*8+j
    unsigned int bits = 0;
    if (u8) {
#pragma unroll
        for (int j = 0; j < 8; ++j)
            if ((raw >> (8 * j)) & 0xFFull) bits |= 1u << j;
    } else {
        const int4* p32 = (const int4*)((const int*)bnd + (size_t)b * SEQ);
        const int4 q0 = p32[t * 2];
        const int4 q1 = p32[t * 2 + 1];
        bits = (q0.x != 0) | ((q0.y != 0) << 1) | ((q0.z != 0) << 2) |
               ((q0.w != 0) << 3) | ((q1.x != 0) << 4) | ((q1.y != 0) << 5) |
               ((q1.z != 0) << 6) | ((q1.w != 0) << 7);
    }
    const int c = __popc(bits);

    // wave-level inclusive scan of c
    int scan = c;
#pragma unroll
    for (int off = 1; off < 64; off <<= 1) {
        const int n = __shfl_up(scan, off);
        if (lane >= off) scan += n;
    }
    const int excl = scan - c;
    if (lane == 63) wave_tot[wid] = scan;
    __syncthreads();
    if (t == 0) {
        int acc = 0;
#pragma unroll
        for (int i = 0; i < 16; ++i) { wave_pref[i] = acc; acc += wave_tot[i]; }
        wave_pref[16] = acc;
    }
    __syncthreads();

    const int total = wave_pref[16];
    int P = wave_pref[wid] + excl;      // boundaries strictly before t*8
    const int s0 = t * 8;
    int* __restrict__ sm = srcmap + (size_t)b * MC;
#pragma unroll
    for (int j = 0; j < 8; ++j) {
        const int s = s0 + j;
        const int v = (bits >> j) & 1;
        const int dest = v ? P : (total + s - P);
        if (dest < MC) sm[dest] = s;
        P += v;
    }
    if (t == 0) ntok_out[b] = (float)total;  // exact in fp32 (<= 8192)
}

// One block per output row: 256 threads x float4 = 4 KB row copy.
// (R4 post-mortem: 4 rows/block + nontemporal regressed 49.5 -> 55.4 us;
//  this 1-row/block L2-cached version is the measured best.)
__global__ void gather_kernel(const float* __restrict__ x,
                              const int* __restrict__ srcmap,
                              float* __restrict__ out, int MC) {
    const int c = blockIdx.x;
    const int b = blockIdx.y;
    const int s = srcmap[(size_t)b * MC + c];
    const float4* __restrict__ in = (const float4*)(x + ((size_t)b * SEQ + s) * DIM);
    float4* __restrict__ o = (float4*)(out + ((size_t)b * MC + c) * DIM);
    o[threadIdx.x] = in[threadIdx.x];
}

extern "C" void kernel_launch(void* const* d_in, const int* in_sizes, int n_in,
                              void* d_out, int out_size, void* d_ws, size_t ws_size,
                              hipStream_t stream) {
    const float* x = (const float*)d_in[0];
    const void* bnd = d_in[1];
    float* out = (float*)d_out;

    // out layout: [B, MC, D] hidden states, then [B] num_tokens (as float32)
    const int MC = (out_size - BATCH) / (BATCH * DIM);

    int* srcmap = (int*)d_ws;

    scan_kernel<<<BATCH, 1024, 0, stream>>>(bnd, srcmap,
                                            out + (size_t)BATCH * MC * DIM, MC);
    gather_kernel<<<dim3(MC, BATCH), 256, 0, stream>>>(x, srcmap, out, MC);
}